// Round 12
// baseline (116.595 us; speedup 1.0000x reference)
//
#include <hip/hip_runtime.h>
#include <hip/hip_bf16.h>
#include <stdint.h>

typedef uint32_t u32;
typedef uint64_t u64;
typedef __bf16 bf16x8 __attribute__((ext_vector_type(8)));
typedef float f32x4 __attribute__((ext_vector_type(4)));
typedef u32 u32x4 __attribute__((ext_vector_type(4)));

#define NB 8
#define NN 2048
#define DIN 256
#define DOUT 256
#define NR 4
#define KTOT (NN * NR)  // 8192

#define XW_BYTES   (NB * DOUT * KTOT * 2)          // 33,554,432
#define PART_BYTES (NB * NN * DOUT * 4)            // 16,777,216 (f32, fallback)
#define WT_BYTES   (NR * DIN * DOUT * 2)           // 524,288
#define PART_ELEMS (NB * NN * DOUT)                // 4,194,304

__device__ __forceinline__ ushort f2bf(float f) {
  union { float f; u32 u; } c; c.f = f;
  return (ushort)((c.u + 0x7FFFu + ((c.u >> 16) & 1u)) >> 16);
}

__device__ __forceinline__ float bf2f(ushort u) {
  union { u32 i; float f; } c; c.i = ((u32)u) << 16; return c.f;
}

__device__ __forceinline__ void gload_lds16(const void* g, void* l) {
  __builtin_amdgcn_global_load_lds(
      (const __attribute__((address_space(1))) u32*)g,
      (__attribute__((address_space(3))) u32*)l, 16, 0, 0);
}

// rel int -> 4 mask bytes (0xFF at slot r-1), packed u32
__device__ __forceinline__ u32 relmask(int v) {
  return v ? (0xFFu << (((u32)(v - 1) & 3u) * 8u)) : 0u;
}

// ---------------- kernel 0: wT[r][o][d] = bf16(w[r][d][o]) ----------------
__global__ void k0_wT(const float* __restrict__ w, ushort* __restrict__ wT) {
  int i = blockIdx.x * 256 + threadIdx.x;   // 262144 total
  int o = i & 255, d = (i >> 8) & 255, r = i >> 16;
  wT[(r * DOUT + o) * DIN + d] = f2bf(w[i]);
}

// ---------------- kernel 1: xwT[b][o][m*4+r] = bf16(x[b,m,:]@W[r][:,o]) ----
__global__ __launch_bounds__(512) void k1_xw(const float* __restrict__ x,
                                             const ushort* __restrict__ wT,
                                             ushort* __restrict__ xwT) {
  __shared__ char smem[65536];
  ushort* As = (ushort*)smem;           // [64 m][32 d]
  ushort* Bs = (ushort*)(smem + 4096);  // [4 r][128 o][32 d]
  const int t = threadIdx.x, l = t & 63, w = t >> 6;
  const int r = w >> 1, oh = w & 1;
  const int blk = blockIdx.x;
  const int b = blk >> 6, rest = blk & 63, mc = rest >> 1, ot = rest & 1;

  f32x4 acc[4][4] = {};
  const int arow = t >> 3, adc = (t & 7) << 2;
  const float* xg = x + ((size_t)(b * NN + mc * 64 + arow) * DIN + adc);

  for (int s = 0; s < 8; ++s) {
    const int d0 = s * 32;
    float4 xv = *(const float4*)(xg + d0);
    ushort4 a4;
    a4.x = f2bf(xv.x); a4.y = f2bf(xv.y); a4.z = f2bf(xv.z); a4.w = f2bf(xv.w);
    *(ushort4*)(As + arow * 32 + adc) = a4;
#pragma unroll
    for (int i = 0; i < 4; ++i) {
      int off = i * 4096 + t * 8;
      int rr = off >> 12, rem = off & 4095, o = rem >> 5, dd = rem & 31;
      const ushort* src = wT + ((size_t)(rr * DOUT + ot * 128 + o) * DIN + d0 + dd);
      gload_lds16(src, Bs + off);
    }
    __syncthreads();
    bf16x8 af[4];
#pragma unroll
    for (int fm = 0; fm < 4; ++fm)
      af[fm] = *(const bf16x8*)(As + (fm * 16 + (l & 15)) * 32 + (l >> 4) * 8);
#pragma unroll
    for (int fo = 0; fo < 4; ++fo) {
      bf16x8 bf = *(const bf16x8*)(Bs + (size_t)(r * 128 + oh * 64 + fo * 16 + (l & 15)) * 32 + (l >> 4) * 8);
#pragma unroll
      for (int fm = 0; fm < 4; ++fm)
        acc[fm][fo] = __builtin_amdgcn_mfma_f32_16x16x32_bf16(af[fm], bf, acc[fm][fo], 0, 0, 0);
    }
    __syncthreads();
  }
  ushort* Cs = (ushort*)smem;
#pragma unroll
  for (int fm = 0; fm < 4; ++fm)
#pragma unroll
    for (int fo = 0; fo < 4; ++fo)
#pragma unroll
      for (int j = 0; j < 4; ++j) {
        int o_loc = oh * 64 + fo * 16 + (l & 15);
        int ml = fm * 16 + (l >> 4) * 4 + j;
        Cs[o_loc * 256 + ml * 4 + r] = f2bf(acc[fm][fo][j]);
      }
  __syncthreads();
#pragma unroll
  for (int i = 0; i < 8; ++i) {
    int el = (i * 512 + t) * 8;
    int o_loc = el >> 8, kp = el & 255;
    *(uint4*)(xwT + (size_t)(b * DOUT + ot * 128 + o_loc) * KTOT + mc * 256 + kp) =
        *(const uint4*)(Cs + el);
  }
}

// ===== kernel 2 v6: byte-mask A + BN=128 + 64KB LDS (2 blocks/CU) =========
// grid 512 logical: b(8).nt(8).ot(2).ks(4); XCD-swizzled (each XCD owns one b)
// 256 thr = 4 waves (2M x 2N), wave 128n x 64o, 8x4 frags 16x16x32, BK=64.
// LDS 64KB: A mask bytes [256 n][64 B] dbuf; B [128 o][64 k] bf16 dbuf.
// A write swizzle unit = (g) ^ (row&7) ^ ((row>>3)&3)  (8B units) — verified
// exactly 2 lanes/slot on both ds_write_b64 and ds_read_b64 (free).
// B via gload_lds, source pre-swizzled (#21). Single end fence
// vmcnt(4)+lgkm0+barrier; rel(s+2) (4 loads) stays in flight (T4).
// Two independent blocks per CU overlap each other's fence drains.
__global__ __launch_bounds__(256, 2) void k2_v6(const int* __restrict__ rel,
                                                const ushort* __restrict__ xwT,
                                                ushort* __restrict__ partb) {
  __shared__ char smem[65536];
  const int t = threadIdx.x, l = t & 63, w = t >> 6;
  const int wm = w >> 1, wn = w & 1;
  const int logical = (blockIdx.x & 7) * 64 + (blockIdx.x >> 3);
  const int b = logical >> 6;
  const int nt = (logical >> 3) & 7;
  const int ot = (logical >> 2) & 1;
  const int ks = logical & 3;

  f32x4 acc[8][4] = {};
  const int fr = l & 15, fq = l >> 4;
  const int rswz = (fr & 7) << 4;   // B read swizzle (16B units)

  char* const Ab0 = smem;            // 16KB: mask bytes [256][64]
  char* const Ab1 = smem + 16384;
  char* const Bb0 = smem + 32768;    // 16KB: B bf16 [128 o][64 k]
  char* const Bb1 = smem + 49152;

  // rel: thread t covers rows r0=(t>>1) and r0+128, half=(t&1) (8 ints each)
  const int arow = t >> 1, half = t & 1;
  const int* relg = rel + ((size_t)(b * NN + nt * 256 + arow)) * NN + ks * 512 + half * 8;
  // A write units for the two rows (row>>3 differs by 16 ≡ 0 mod 4 → same)
  const u32 awx = ((u32)arow & 7u) ^ (((u32)arow >> 3) & 3u);
  char* const rowA0a = Ab0 + arow * 64;
  char* const rowA0b = Ab0 + (arow + 128) * 64;
  char* const rowA1a = Ab1 + arow * 64;
  char* const rowA1b = Ab1 + (arow + 128) * 64;

  // B staging: thread t owns rows o=(t>>3)+32*i, source col pre-swizzled
  const int brow = t >> 3;
  const int kd = (((t & 7) ^ ((t >> 3) & 7)) << 3);  // element offset
  const ushort* xwb = xwT + (size_t)(b * DOUT + ot * 128) * KTOT + ks * 2048;

  int4 rs0a, rs0b, rs0c, rs0d, rs1a, rs1b, rs1c, rs1d;  // rel(k): set k&1

#define GLD_B(S, BB)                                                           \
  {                                                                            \
    _Pragma("unroll") for (int i = 0; i < 4; ++i)                              \
      gload_lds16(xwb + (size_t)(brow + 32 * i) * KTOT + (S) * 64 + kd,        \
                  (BB) + i * 4096 + t * 16);                                   \
  }

#define RELLOAD(S, RA, RB, RC, RD)                                             \
  RA = *(const int4*)(relg + (S) * 16);                                        \
  RB = *(const int4*)(relg + (S) * 16 + 4);                                    \
  RC = *(const int4*)(relg + (size_t)128 * NN + (S) * 16);                     \
  RD = *(const int4*)(relg + (size_t)128 * NN + (S) * 16 + 4);

// one row-half: 8 ints -> 4 ds_write_b64 at units (half*4+jj)^awx
#define EXPROW(ROWP, V0, V1)                                                   \
  {                                                                            \
    int vv[8] = {V0.x, V0.y, V0.z, V0.w, V1.x, V1.y, V1.z, V1.w};              \
    _Pragma("unroll") for (int jj = 0; jj < 4; ++jj) {                         \
      u64 mw = (u64)relmask(vv[2 * jj]) | ((u64)relmask(vv[2 * jj + 1]) << 32);\
      *(u64*)((ROWP) + ((((u32)(half * 4 + jj)) ^ awx) * 8)) = mw;             \
    }                                                                          \
  }

#define RDB(BV, BB, KK)                                                        \
  _Pragma("unroll") for (int fo = 0; fo < 4; ++fo)                             \
    BV[fo] = *(const bf16x8*)((BB) + (wn * 64 + fo * 16 + fr) * 128 +          \
                              (((KK) * 64 + fq * 16) ^ rswz));

// frag (f, KK): row = wm*128+f*16+fr; unit = (KK*4+fq)^(fr&7)^((f*2+(fr>>3))&3)
#define RDA_K(AR, AB, KK)                                                      \
  _Pragma("unroll") for (int f = 0; f < 8; ++f)                                \
    AR[f] = *(const int2*)((AB) + (wm * 128 + f * 16 + fr) * 64 +              \
        (((((KK) * 4 + fq)) ^ (fr & 7) ^ ((f * 2 + (fr >> 3)) & 3)) * 8));

// unpack 8 mask bytes -> one-hot bf16x8 (exact 1.0), then 4 MFMAs
#define MFMA1(FM, Q, BV)                                                       \
  {                                                                            \
    u32x4 uu;                                                                  \
    uu.x = __builtin_amdgcn_perm((u32)(Q).x, (u32)(Q).x, 0x01010000u) & 0x3F803F80u; \
    uu.y = __builtin_amdgcn_perm((u32)(Q).x, (u32)(Q).x, 0x03030202u) & 0x3F803F80u; \
    uu.z = __builtin_amdgcn_perm((u32)(Q).y, (u32)(Q).y, 0x01010000u) & 0x3F803F80u; \
    uu.w = __builtin_amdgcn_perm((u32)(Q).y, (u32)(Q).y, 0x03030202u) & 0x3F803F80u; \
    union { u32x4 u; bf16x8 b; } cv; cv.u = uu;                                \
    _Pragma("unroll") for (int fo = 0; fo < 4; ++fo)                           \
      acc[FM][fo] = __builtin_amdgcn_mfma_f32_16x16x32_bf16(                   \
          cv.b, BV[fo], acc[FM][fo], 0, 0, 0);                                 \
  }

#define MFMAH(AR, BV)                                                          \
  __builtin_amdgcn_s_setprio(1);                                               \
  _Pragma("unroll") for (int f = 0; f < 8; ++f) MFMA1(f, AR[f], BV);           \
  __builtin_amdgcn_s_setprio(0);

#define ENDF(VMS)                                                              \
  asm volatile("s_waitcnt vmcnt(" VMS ") lgkmcnt(0)" ::: "memory");            \
  __builtin_amdgcn_s_barrier();                                                \
  __builtin_amdgcn_sched_barrier(0);

// One K-step: P = S&1 buffers current, Q staged/expanded.
#define STEP(S, P, Q, STG, REL, EXP, VMS)                                      \
  {                                                                            \
    bf16x8 bv0[4], bv1[4];                                                     \
    int2 a0[8], a1[8];                                                         \
    RDB(bv0, Bb##P, 0);                                                        \
    RDA_K(a0, Ab##P, 0);                                                       \
    if (STG) { GLD_B((S) + 1, Bb##Q); }                                        \
    __builtin_amdgcn_sched_barrier(0);                                         \
    if (REL) { RELLOAD((S) + 2, rs##P##a, rs##P##b, rs##P##c, rs##P##d); }     \
    __builtin_amdgcn_sched_barrier(0);                                         \
    MFMAH(a0, bv0);                                                            \
    RDB(bv1, Bb##P, 1);                                                        \
    RDA_K(a1, Ab##P, 1);                                                       \
    if (EXP) { EXPROW(rowA##Q##a, rs##Q##a, rs##Q##b);                         \
               EXPROW(rowA##Q##b, rs##Q##c, rs##Q##d); }                       \
    MFMAH(a1, bv1);                                                            \
    ENDF(VMS);                                                                 \
  }

  // prologue: B(0) staged; rel(0),rel(1) loaded; A(0) expanded
  GLD_B(0, Bb0);
  __builtin_amdgcn_sched_barrier(0);
  RELLOAD(0, rs0a, rs0b, rs0c, rs0d);
  RELLOAD(1, rs1a, rs1b, rs1c, rs1d);
  EXPROW(rowA0a, rs0a, rs0b);
  EXPROW(rowA0b, rs0c, rs0d);   // compiler auto-waits rel(0)
  ENDF("4");                    // B(0)+rel(0) retired; rel(1) in flight

  for (int s = 0; s < 30; s += 2) {
    STEP(s, 0, 1, 1, 1, 1, "4");
    STEP(s + 1, 1, 0, 1, 1, 1, "4");
  }
  STEP(30, 0, 1, 1, 0, 1, "0");  // stages B(31); expands A(31); drain all
  {  // s = 31: final compute, no staging, no trailing fence
    bf16x8 bv0[4], bv1[4];
    int2 a0[8], a1[8];
    RDB(bv0, Bb1, 0);
    RDA_K(a0, Ab1, 0);
    MFMAH(a0, bv0);
    RDB(bv1, Bb1, 1);
    RDA_K(a1, Ab1, 1);
    MFMAH(a1, bv1);
  }

  ushort* dst = partb + (size_t)ks * PART_ELEMS;
#pragma unroll
  for (int fm = 0; fm < 8; ++fm)
#pragma unroll
    for (int fo = 0; fo < 4; ++fo) {
      int n = nt * 256 + wm * 128 + fm * 16 + fq * 4;
      int o = ot * 128 + wn * 64 + fo * 16 + fr;
#pragma unroll
      for (int j = 0; j < 4; ++j)
        dst[(size_t)(b * NN + n + j) * DOUT + o] = f2bf(acc[fm][fo][j]);
    }
#undef STEP
#undef ENDF
#undef MFMAH
#undef MFMA1
#undef RDA_K
#undef RDB
#undef EXPROW
#undef RELLOAD
#undef GLD_B
}

// ---------------- kernel 3: out = sum of 4 bf16 partials + bias -----------
__global__ void k3_sum(float* __restrict__ out, const ushort* __restrict__ partb,
                       const float* __restrict__ bias) {
  int i = blockIdx.x * 256 + threadIdx.x;  // float4-group, 1048576 total
  float4 s = ((const float4*)bias)[i & 63];
#pragma unroll
  for (int p = 0; p < 4; ++p) {
    ushort4 v = ((const ushort4*)(partb + (size_t)p * PART_ELEMS))[i];
    s.x += bf2f(v.x); s.y += bf2f(v.y); s.z += bf2f(v.z); s.w += bf2f(v.w);
  }
  ((float4*)out)[i] = s;
}

// ============= fallback path: exact R4 kernels (proven, 50.9MB ws) ========
__global__ __launch_bounds__(256, 2) void k2_r4(const int* __restrict__ rel,
                                                const ushort* __restrict__ xwT,
                                                float* __restrict__ out,
                                                float* __restrict__ part) {
  __shared__ char smem[81920];
  const int t = threadIdx.x, l = t & 63, w = t >> 6;
  const int wr = w >> 1, wc = w & 1;
  const int logical = (blockIdx.x & 7) * 64 + (blockIdx.x >> 3);
  const int b = logical >> 6;
  const int nt = (logical >> 2) & 15;
  const int ks = (logical >> 1) & 1;
  const int ot = logical & 1;

  f32x4 acc[4][4] = {};
  const int arow = t >> 1, half = t & 1;
  const int* relg = rel + ((size_t)(b * NN + nt * 128 + arow) * NN + ks * 1024 + half * 8);
  const ushort* xwb = xwT + (size_t)(b * DOUT + ot * 128) * KTOT + ks * 4096;

  char* const Ab0 = smem;
  char* const Ab1 = smem + 16384;
  char* const Bb0 = smem + 32768;
  char* const Bb1 = smem + 49152;
  char* const Bb2 = smem + 65536;

  const int brow = t >> 3;
  const int kd = (((t & 7) ^ ((t >> 3) & 7)) << 3);
  const int aswz = (arow & 7) << 4;
  const int fr = l & 15, fq = l >> 4;
  const int rswz = (fr & 7) << 4;

  int4 rsA0, rsB0, rsA1, rsB1;

#define STAGE_B(S, BBASE)                                                      \
  {                                                                            \
    _Pragma("unroll") for (int i = 0; i < 4; ++i)                              \
      gload_lds16(xwb + (size_t)(brow + 32 * i) * KTOT + (S) * 64 + kd,        \
                  (BBASE) + i * 4096 + t * 16);                                \
  }
#define RELLOAD(S, RA, RB)                                                     \
  RA = *(const int4*)(relg + (S) * 16);                                        \
  RB = *(const int4*)(relg + (S) * 16 + 4);
#define EXPAND_A(ABASE, V0, V1)                                                \
  {                                                                            \
    char* rowp = (ABASE) + arow * 128;                                         \
    int vv[8] = {V0.x, V0.y, V0.z, V0.w, V1.x, V1.y, V1.z, V1.w};              \
    _Pragma("unroll") for (int p = 0; p < 4; ++p) {                            \
      int va = vv[2 * p], vb = vv[2 * p + 1];                                  \
      u32 sa = ((u32)(va - 1) & 3u) * 16u;                                     \
      u32 sb = ((u32)(vb - 1) & 3u) * 16u;                                     \
      u64 ha = va ? (0x3F80ull << sa) : 0ull;                                  \
      u64 hb = vb ? (0x3F80ull << sb) : 0ull;                                  \
      u32x4 e = {(u32)ha, (u32)(ha >> 32), (u32)hb, (u32)(hb >> 32)};          \
      *(u32x4*)(rowp + ((half * 64 + p * 16) ^ aswz)) = e;                     \
    }                                                                          \
  }
#define BARV6()                                                                \
  asm volatile("s_waitcnt vmcnt(6) lgkmcnt(0)" ::: "memory");                  \
  __builtin_amdgcn_s_barrier();                                                \
  __builtin_amdgcn_sched_barrier(0);
#define BARV0()                                                                \
  asm volatile("s_waitcnt vmcnt(0) lgkmcnt(0)" ::: "memory");                  \
  __builtin_amdgcn_s_barrier();                                                \
  __builtin_amdgcn_sched_barrier(0);
#define MFMA_STEP(AC, BC)                                                      \
  __builtin_amdgcn_s_setprio(1);                                               \
  _Pragma("unroll") for (int kk = 0; kk < 2; ++kk) {                           \
    bf16x8 af[4], bfv[4];                                                      \
    const int colb = (kk * 64 + fq * 16) ^ rswz;                               \
    _Pragma("unroll") for (int fm = 0; fm < 4; ++fm)                           \
      af[fm] = *(const bf16x8*)((AC) + (wr * 64 + fm * 16 + fr) * 128 + colb); \
    _Pragma("unroll") for (int fo = 0; fo < 4; ++fo)                           \
      bfv[fo] = *(const bf16x8*)((BC) + (wc * 64 + fo * 16 + fr) * 128 + colb);\
    _Pragma("unroll") for (int fm = 0; fm < 4; ++fm)                           \
      _Pragma("unroll") for (int fo = 0; fo < 4; ++fo)                         \
        acc[fm][fo] = __builtin_amdgcn_mfma_f32_16x16x32_bf16(                 \
            af[fm], bfv[fo], acc[fm][fo], 0, 0, 0);                            \
  }                                                                            \
  __builtin_amdgcn_s_setprio(0);
#define BODY(S, ACUR, BCUR, ANXT, RLA, RLB, RCA, RCB, BSTG)                    \
  {                                                                            \
    STAGE_B((S) + 2, BSTG);                                                    \
    RELLOAD((S) + 2, RLA, RLB);                                                \
    MFMA_STEP(ACUR, BCUR);                                                     \
    EXPAND_A(ANXT, RCA, RCB);                                                  \
    BARV6();                                                                   \
  }

  STAGE_B(0, Bb0);
  RELLOAD(0, rsA0, rsB0);
  STAGE_B(1, Bb1);
  RELLOAD(1, rsA1, rsB1);
  EXPAND_A(Ab0, rsA0, rsB0);
  BARV6();

  for (int s = 0; s < 60; s += 6) {
    BODY(s + 0, Ab0, Bb0, Ab1, rsA0, rsB0, rsA1, rsB1, Bb2);
    BODY(s + 1, Ab1, Bb1, Ab0, rsA1, rsB1, rsA0, rsB0, Bb0);
    BODY(s + 2, Ab0, Bb2, Ab1, rsA0, rsB0, rsA1, rsB1, Bb1);
    BODY(s + 3, Ab1, Bb0, Ab0, rsA1, rsB1, rsA0, rsB0, Bb2);
    BODY(s + 4, Ab0, Bb1, Ab1, rsA0, rsB0, rsA1, rsB1, Bb0);
    BODY(s + 5, Ab1, Bb2, Ab0, rsA1, rsB1, rsA0, rsB0, Bb1);
  }
  BODY(60, Ab0, Bb0, Ab1, rsA0, rsB0, rsA1, rsB1, Bb2);
  BODY(61, Ab1, Bb1, Ab0, rsA1, rsB1, rsA0, rsB0, Bb0);
  {
    MFMA_STEP(Ab0, Bb2);
    EXPAND_A(Ab1, rsA1, rsB1);
    BARV0();
  }
  {
    MFMA_STEP(Ab1, Bb0);
  }

  float* dst = ks ? part : out;
#pragma unroll
  for (int fm = 0; fm < 4; ++fm)
#pragma unroll
    for (int fo = 0; fo < 4; ++fo) {
      int n = nt * 128 + wr * 64 + fm * 16 + fq * 4;
      int o = ot * 128 + wc * 64 + fo * 16 + fr;
#pragma unroll
      for (int j = 0; j < 4; ++j)
        dst[(size_t)(b * NN + n + j) * DOUT + o] = acc[fm][fo][j];
    }
#undef BODY
#undef MFMA_STEP
#undef BARV6
#undef BARV0
#undef EXPAND_A
#undef RELLOAD
#undef STAGE_B
}

__global__ void k3_r4(float* __restrict__ out, const float* __restrict__ part,
                      const float* __restrict__ bias) {
  int i = blockIdx.x * 256 + threadIdx.x;
  float4 o = ((const float4*)out)[i];
  float4 p = ((const float4*)part)[i];
  float4 bv = ((const float4*)bias)[i & 63];
  float4 rr;
  rr.x = o.x + p.x + bv.x;
  rr.y = o.y + p.y + bv.y;
  rr.z = o.z + p.z + bv.z;
  rr.w = o.w + p.w + bv.w;
  ((float4*)out)[i] = rr;
}

extern "C" void kernel_launch(void* const* d_in, const int* in_sizes, int n_in,
                              void* d_out, int out_size, void* d_ws, size_t ws_size,
                              hipStream_t stream) {
  const float* x = (const float*)d_in[0];
  const int* rel = (const int*)d_in[2];
  const float* wgt = (const float*)d_in[3];
  const float* bias = (const float*)d_in[4];
  float* out = (float*)d_out;
  char* ws = (char*)d_ws;

  const size_t partb_bytes = (size_t)PART_ELEMS * 2 * 4;  // 4 bf16 partials
  const size_t need_big = (size_t)XW_BYTES + partb_bytes + WT_BYTES;
  if (ws_size >= need_big) {
    ushort* xwT = (ushort*)ws;
    ushort* partb = (ushort*)(ws + XW_BYTES);
    ushort* wT = (ushort*)(ws + XW_BYTES + partb_bytes);
    k0_wT<<<1024, 256, 0, stream>>>(wgt, wT);
    k1_xw<<<512, 512, 0, stream>>>(x, wT, xwT);
    k2_v6<<<512, 256, 0, stream>>>(rel, xwT, partb);
    k3_sum<<<4096, 256, 0, stream>>>(out, partb, bias);
  } else {
    ushort* xwT = (ushort*)ws;
    float* part = (float*)(ws + XW_BYTES);
    ushort* wT = (ushort*)(ws + XW_BYTES + PART_BYTES);
    k0_wT<<<1024, 256, 0, stream>>>(wgt, wT);
    k1_xw<<<512, 512, 0, stream>>>(x, wT, xwT);
    k2_r4<<<512, 256, 0, stream>>>(rel, xwT, out, part);
    k3_r4<<<4096, 256, 0, stream>>>(out, part, bias);
  }
}

// Round 13
// 108.245 us; speedup vs baseline: 1.0771x; 1.0771x over previous
//
#include <hip/hip_runtime.h>
#include <hip/hip_bf16.h>
#include <stdint.h>

typedef uint32_t u32;
typedef uint64_t u64;
typedef __bf16 bf16x8 __attribute__((ext_vector_type(8)));
typedef float f32x4 __attribute__((ext_vector_type(4)));
typedef u32 u32x4 __attribute__((ext_vector_type(4)));

#define NB 8
#define NN 2048
#define DIN 256
#define DOUT 256
#define NR 4
#define KTOT (NN * NR)  // 8192

#define XW_BYTES   (NB * DOUT * KTOT * 2)          // 33,554,432
#define PART_BYTES (NB * NN * DOUT * 4)            // 16,777,216 (f32, fallback)
#define WT_BYTES   (NR * DIN * DOUT * 2)           // 524,288
#define PART_ELEMS (NB * NN * DOUT)                // 4,194,304

__device__ __forceinline__ ushort f2bf(float f) {
  union { float f; u32 u; } c; c.f = f;
  return (ushort)((c.u + 0x7FFFu + ((c.u >> 16) & 1u)) >> 16);
}

__device__ __forceinline__ float bf2f(ushort u) {
  union { u32 i; float f; } c; c.i = ((u32)u) << 16; return c.f;
}

__device__ __forceinline__ void gload_lds16(const void* g, void* l) {
  __builtin_amdgcn_global_load_lds(
      (const __attribute__((address_space(1))) u32*)g,
      (__attribute__((address_space(3))) u32*)l, 16, 0, 0);
}

// ---------------- kernel 0: wT[r][o][d] = bf16(w[r][d][o]) ----------------
__global__ void k0_wT(const float* __restrict__ w, ushort* __restrict__ wT) {
  int i = blockIdx.x * 256 + threadIdx.x;   // 262144 total
  int o = i & 255, d = (i >> 8) & 255, r = i >> 16;
  wT[(r * DOUT + o) * DIN + d] = f2bf(w[i]);
}

// ===== kernel 1 v2: xwT[b][o][m*4+r] — pipelined + conflict-free LDS ======
// grid 512: b(8) x mc(32, m-tile 64) x ot(2, o-tile 128). 512 thr = 8 waves,
// wave = (r = w>>1, oh = w&1): C_r[64 m][64 o], 4x4 frags 16x16x32, BK=32.
// LDS 72KB: As dbuf 2x4KB (f32->bf16 reg-convert, swizzled write) +
// Bs dbuf 2x32KB (gload_lds, source pre-swizzled). 16B-unit XOR swizzle
// unit^=(row&3) on 64B rows: frag reads go 8-way -> 2-way (free).
// Single fence per step: vmcnt(0)+lgkm0+barrier after MFMA; B(s+1) glds
// issued at step start get the whole MFMA phase to land.
__global__ __launch_bounds__(512) void k1_xw(const float* __restrict__ x,
                                             const ushort* __restrict__ wT,
                                             ushort* __restrict__ xwT) {
  __shared__ char smem[73728];
  char* const Ab0 = smem;            // 4KB  [64 m][32 d] bf16, swizzled
  char* const Ab1 = smem + 4096;
  char* const Bb0 = smem + 8192;     // 32KB [4 r][128 o][32 d] bf16, swizzled
  char* const Bb1 = smem + 40960;
  const int t = threadIdx.x, l = t & 63, w = t >> 6;
  const int r = w >> 1, oh = w & 1;
  const int blk = blockIdx.x;
  const int b = blk >> 6, rest = blk & 63, mc = rest >> 1, ot = rest & 1;

  f32x4 acc[4][4] = {};
  const int fr = l & 15, fq = l >> 4;
  const int ru = ((fq ^ (fr & 3)) << 4);  // swizzled 16B-unit byte offset

  // A staging: thread t stages row arow=t>>3, 4 elems at (t&7)*4; write 8B
  const int arow = t >> 3;
  const int abyte = ((((t & 7) >> 1) ^ (arow & 3)) << 4) + (t & 1) * 8;
  const float* xg = x + ((size_t)(b * NN + mc * 64 + arow) * DIN + (t & 7) * 4);

  // B staging: 4 glds/step; i-th: LDS row = i*128 + (t>>2), unit = t&3
  // holds logical unit (t&3)^((t>>2)&3) -> source dd pre-swizzled
  const int bdd = (((t & 3) ^ ((t >> 2) & 3)) << 3);
  const int bro = (t >> 2);  // o within 128

#define K1_GLDB(D0, BB)                                                        \
  {                                                                            \
    _Pragma("unroll") for (int i = 0; i < 4; ++i) {                            \
      const ushort* src = wT + ((size_t)(i * DOUT + ot * 128 + bro) * DIN +    \
                                (D0) + bdd);                                   \
      gload_lds16(src, (BB) + i * 8192 + t * 16);                              \
    }                                                                          \
  }

#define K1_WRA(AB, XV)                                                         \
  {                                                                            \
    ushort4 a4;                                                                \
    a4.x = f2bf((XV).x); a4.y = f2bf((XV).y);                                  \
    a4.z = f2bf((XV).z); a4.w = f2bf((XV).w);                                  \
    *(ushort4*)((AB) + arow * 64 + abyte) = a4;                                \
  }

#define K1_MFMA(AB, BB)                                                        \
  {                                                                            \
    bf16x8 af[4];                                                              \
    __builtin_amdgcn_s_setprio(1);                                             \
    _Pragma("unroll") for (int fm = 0; fm < 4; ++fm)                           \
      af[fm] = *(const bf16x8*)((AB) + (fm * 16 + fr) * 64 + ru);              \
    _Pragma("unroll") for (int fo = 0; fo < 4; ++fo) {                         \
      bf16x8 bf = *(const bf16x8*)((BB) + (size_t)(r * 128 + oh * 64 +         \
                                   fo * 16 + fr) * 64 + ru);                   \
      _Pragma("unroll") for (int fm = 0; fm < 4; ++fm)                         \
        acc[fm][fo] = __builtin_amdgcn_mfma_f32_16x16x32_bf16(                 \
            af[fm], bf, acc[fm][fo], 0, 0, 0);                                 \
    }                                                                          \
    __builtin_amdgcn_s_setprio(0);                                             \
  }

#define K1_ENDF()                                                              \
  asm volatile("s_waitcnt vmcnt(0) lgkmcnt(0)" ::: "memory");                  \
  __builtin_amdgcn_s_barrier();                                                \
  __builtin_amdgcn_sched_barrier(0);

// step S: stage B(S+1)->BQ + x(S+1)->reg, MFMA(S) from AP/BP, write A(S+1)->AQ
#define K1_STEP(S, AP, BP, AQ, BQ)                                             \
  {                                                                            \
    K1_GLDB((S + 1) * 32, BQ);                                                 \
    __builtin_amdgcn_sched_barrier(0);                                         \
    float4 xv = *(const float4*)(xg + (S + 1) * 32);                           \
    K1_MFMA(AP, BP);                                                           \
    K1_WRA(AQ, xv);                                                            \
    K1_ENDF();                                                                 \
  }

  // prologue: B(0) glds; x(0) -> Ab0
  K1_GLDB(0, Bb0);
  __builtin_amdgcn_sched_barrier(0);
  {
    float4 xv = *(const float4*)(xg);
    K1_WRA(Ab0, xv);
  }
  K1_ENDF();

  K1_STEP(0, Ab0, Bb0, Ab1, Bb1);
  K1_STEP(1, Ab1, Bb1, Ab0, Bb0);
  K1_STEP(2, Ab0, Bb0, Ab1, Bb1);
  K1_STEP(3, Ab1, Bb1, Ab0, Bb0);
  K1_STEP(4, Ab0, Bb0, Ab1, Bb1);
  K1_STEP(5, Ab1, Bb1, Ab0, Bb0);
  K1_STEP(6, Ab0, Bb0, Ab1, Bb1);
  K1_MFMA(Ab1, Bb1);  // step 7, no staging
  __syncthreads();

  // epilogue repack through LDS: Cs[128 o][256 kp] (overlaps dead buffers)
  ushort* Cs = (ushort*)smem;
#pragma unroll
  for (int fm = 0; fm < 4; ++fm)
#pragma unroll
    for (int fo = 0; fo < 4; ++fo)
#pragma unroll
      for (int j = 0; j < 4; ++j) {
        int o_loc = oh * 64 + fo * 16 + fr;
        int ml = fm * 16 + fq * 4 + j;
        Cs[o_loc * 256 + ml * 4 + r] = f2bf(acc[fm][fo][j]);
      }
  __syncthreads();
#pragma unroll
  for (int i = 0; i < 8; ++i) {
    int el = (i * 512 + t) * 8;
    int o_loc = el >> 8, kp = el & 255;
    *(uint4*)(xwT + (size_t)(b * DOUT + ot * 128 + o_loc) * KTOT + mc * 256 + kp) =
        *(const uint4*)(Cs + el);
  }
#undef K1_STEP
#undef K1_ENDF
#undef K1_MFMA
#undef K1_WRA
#undef K1_GLDB
}

// ============= kernel 2 v2 (R8 best, 916 TF eff): ONE barrier per K-step ==
__global__ __launch_bounds__(512, 2) void k2_v2(const int* __restrict__ rel,
                                                const ushort* __restrict__ xwT,
                                                ushort* __restrict__ partb) {
  __shared__ char smem[131072];
  const int t = threadIdx.x, l = t & 63, w = t >> 6;
  const int wm = w >> 2, wn = w & 3;
  const int logical = (blockIdx.x & 7) * 32 + (blockIdx.x >> 3);
  const int b = logical >> 5;
  const int nt = (logical >> 2) & 7;
  const int ks = logical & 3;

  f32x4 acc[8][4] = {};
  const int fr = l & 15, fq = l >> 4;
  const int rswz = (fr & 7) << 4;

  char* const Ab0 = smem;
  char* const Ab1 = smem + 32768;
  char* const Bb0 = smem + 65536;
  char* const Bb1 = smem + 98304;

  const int arow = t >> 1, half = t & 1;
  const int aswz = (arow & 7) << 4;
  const int* relg = rel + ((size_t)(b * NN + nt * 256 + arow)) * NN + ks * 512 + half * 8;

  const int brow = t >> 3;
  const int kd = (((t & 7) ^ ((t >> 3) & 7)) << 3);
  const ushort* xwb = xwT + (size_t)b * DOUT * KTOT + ks * 2048;

  int4 rs0a, rs0b, rs1a, rs1b;

#define GLD_ALL(S, BB)                                                         \
  {                                                                            \
    _Pragma("unroll") for (int i = 0; i < 4; ++i)                              \
      gload_lds16(xwb + (size_t)(brow + 64 * i) * KTOT + (S) * 64 + kd,        \
                  (BB) + i * 8192 + t * 16);                                   \
  }

#define RELLOAD(S, RA, RB)                                                     \
  RA = *(const int4*)(relg + (S) * 16);                                        \
  RB = *(const int4*)(relg + (S) * 16 + 4);

#define EXPAND_A(ABASE, V0, V1)                                                \
  {                                                                            \
    char* rowp = (ABASE) + arow * 128;                                         \
    int vv[8] = {V0.x, V0.y, V0.z, V0.w, V1.x, V1.y, V1.z, V1.w};              \
    _Pragma("unroll") for (int p = 0; p < 4; ++p) {                            \
      int va = vv[2 * p], vb = vv[2 * p + 1];                                  \
      u32 sa = ((u32)(va - 1) & 3u) * 16u;                                     \
      u32 sb = ((u32)(vb - 1) & 3u) * 16u;                                     \
      u64 ha = va ? (0x3F80ull << sa) : 0ull;                                  \
      u64 hb = vb ? (0x3F80ull << sb) : 0ull;                                  \
      u32x4 e = {(u32)ha, (u32)(ha >> 32), (u32)hb, (u32)(hb >> 32)};          \
      *(u32x4*)(rowp + ((half * 64 + p * 16) ^ aswz)) = e;                     \
    }                                                                          \
  }

#define RDB(BV, BB, KK)                                                        \
  _Pragma("unroll") for (int fo = 0; fo < 4; ++fo)                             \
    BV[fo] = *(const bf16x8*)((BB) + (wn * 64 + fo * 16 + fr) * 128 +          \
                              (((KK) * 64 + fq * 16) ^ rswz));

#define RDA(AV, AB, FM0, KK)                                                   \
  _Pragma("unroll") for (int i = 0; i < 4; ++i)                                \
    AV[i] = *(const bf16x8*)((AB) + (wm * 128 + ((FM0) + i) * 16 + fr) * 128 + \
                             (((KK) * 64 + fq * 16) ^ rswz));

#define MFMA4(FM0, AV, BV)                                                     \
  __builtin_amdgcn_s_setprio(1);                                               \
  _Pragma("unroll") for (int i = 0; i < 4; ++i)                                \
    _Pragma("unroll") for (int fo = 0; fo < 4; ++fo)                           \
      acc[(FM0) + i][fo] = __builtin_amdgcn_mfma_f32_16x16x32_bf16(            \
          AV[i], BV[fo], acc[(FM0) + i][fo], 0, 0, 0);                         \
  __builtin_amdgcn_s_setprio(0);

#define ENDFENCE(VMS)                                                          \
  asm volatile("s_waitcnt vmcnt(" VMS ") lgkmcnt(0)" ::: "memory");            \
  __builtin_amdgcn_s_barrier();                                                \
  __builtin_amdgcn_sched_barrier(0);

#define STEP(S, P, Q, STG, REL, EXP, VMS)                                      \
  {                                                                            \
    bf16x8 b0[4], b1[4], aA[4], aB[4], aC[4], aD[4];                           \
    RDB(b0, Bb##P, 0);                                                         \
    RDA(aA, Ab##P, 0, 0);                                                      \
    if (STG) { GLD_ALL((S) + 1, Bb##Q); }                                      \
    __builtin_amdgcn_sched_barrier(0);                                         \
    if (REL) { RELLOAD((S) + 2, rs##P##a, rs##P##b); }                         \
    RDA(aB, Ab##P, 4, 0);                                                      \
    MFMA4(0, aA, b0);                                                          \
    RDA(aC, Ab##P, 0, 1);                                                      \
    if (EXP) { EXPAND_A(Ab##Q, rs##Q##a, rs##Q##b); }                          \
    MFMA4(4, aB, b0);                                                          \
    RDB(b1, Bb##P, 1);                                                         \
    RDA(aD, Ab##P, 4, 1);                                                      \
    MFMA4(0, aC, b1);                                                          \
    MFMA4(4, aD, b1);                                                          \
    ENDFENCE(VMS);                                                             \
  }

  GLD_ALL(0, Bb0);
  __builtin_amdgcn_sched_barrier(0);
  RELLOAD(0, rs0a, rs0b);
  RELLOAD(1, rs1a, rs1b);
  EXPAND_A(Ab0, rs0a, rs0b);
  ENDFENCE("4");

  for (int s = 0; s < 30; s += 2) {
    STEP(s, 0, 1, 1, 1, 1, "2");
    STEP(s + 1, 1, 0, 1, 1, 1, "2");
  }
  STEP(30, 0, 1, 1, 0, 1, "0");
  {  // s = 31: final compute
    bf16x8 b0[4], b1[4], aA[4], aB[4], aC[4], aD[4];
    RDB(b0, Bb1, 0);
    RDA(aA, Ab1, 0, 0);
    RDA(aB, Ab1, 4, 0);
    MFMA4(0, aA, b0);
    RDA(aC, Ab1, 0, 1);
    MFMA4(4, aB, b0);
    RDB(b1, Bb1, 1);
    RDA(aD, Ab1, 4, 1);
    MFMA4(0, aC, b1);
    MFMA4(4, aD, b1);
  }

  ushort* dst = partb + (size_t)ks * PART_ELEMS;
#pragma unroll
  for (int fm = 0; fm < 8; ++fm)
#pragma unroll
    for (int fo = 0; fo < 4; ++fo) {
      int n = nt * 256 + wm * 128 + fm * 16 + fq * 4;
      int o = wn * 64 + fo * 16 + fr;
#pragma unroll
      for (int j = 0; j < 4; ++j)
        dst[(size_t)(b * NN + n + j) * DOUT + o] = f2bf(acc[fm][fo][j]);
    }
#undef STEP
#undef ENDFENCE
#undef MFMA4
#undef RDA
#undef RDB
#undef EXPAND_A
#undef RELLOAD
#undef GLD_ALL
}

// ---------------- kernel 3: out = sum of 4 bf16 partials + bias -----------
__global__ void k3_sum(float* __restrict__ out, const ushort* __restrict__ partb,
                       const float* __restrict__ bias) {
  int i = blockIdx.x * 256 + threadIdx.x;  // float4-group, 1048576 total
  float4 s = ((const float4*)bias)[i & 63];
#pragma unroll
  for (int p = 0; p < 4; ++p) {
    ushort4 v = ((const ushort4*)(partb + (size_t)p * PART_ELEMS))[i];
    s.x += bf2f(v.x); s.y += bf2f(v.y); s.z += bf2f(v.z); s.w += bf2f(v.w);
  }
  ((float4*)out)[i] = s;
}

// ============= fallback path: exact R4 kernels (proven, 50.9MB ws) ========
__global__ __launch_bounds__(256, 2) void k2_r4(const int* __restrict__ rel,
                                                const ushort* __restrict__ xwT,
                                                float* __restrict__ out,
                                                float* __restrict__ part) {
  __shared__ char smem[81920];
  const int t = threadIdx.x, l = t & 63, w = t >> 6;
  const int wr = w >> 1, wc = w & 1;
  const int logical = (blockIdx.x & 7) * 64 + (blockIdx.x >> 3);
  const int b = logical >> 6;
  const int nt = (logical >> 2) & 15;
  const int ks = (logical >> 1) & 1;
  const int ot = logical & 1;

  f32x4 acc[4][4] = {};
  const int arow = t >> 1, half = t & 1;
  const int* relg = rel + ((size_t)(b * NN + nt * 128 + arow) * NN + ks * 1024 + half * 8);
  const ushort* xwb = xwT + (size_t)(b * DOUT + ot * 128) * KTOT + ks * 4096;

  char* const Ab0 = smem;
  char* const Ab1 = smem + 16384;
  char* const Bb0 = smem + 32768;
  char* const Bb1 = smem + 49152;
  char* const Bb2 = smem + 65536;

  const int brow = t >> 3;
  const int kd = (((t & 7) ^ ((t >> 3) & 7)) << 3);
  const int aswz = (arow & 7) << 4;
  const int fr = l & 15, fq = l >> 4;
  const int rswz = (fr & 7) << 4;

  int4 rsA0, rsB0, rsA1, rsB1;

#define STAGE_B(S, BBASE)                                                      \
  {                                                                            \
    _Pragma("unroll") for (int i = 0; i < 4; ++i)                              \
      gload_lds16(xwb + (size_t)(brow + 32 * i) * KTOT + (S) * 64 + kd,        \
                  (BBASE) + i * 4096 + t * 16);                                \
  }
#define RELLOAD(S, RA, RB)                                                     \
  RA = *(const int4*)(relg + (S) * 16);                                        \
  RB = *(const int4*)(relg + (S) * 16 + 4);
#define EXPAND_A(ABASE, V0, V1)                                                \
  {                                                                            \
    char* rowp = (ABASE) + arow * 128;                                         \
    int vv[8] = {V0.x, V0.y, V0.z, V0.w, V1.x, V1.y, V1.z, V1.w};              \
    _Pragma("unroll") for (int p = 0; p < 4; ++p) {                            \
      int va = vv[2 * p], vb = vv[2 * p + 1];                                  \
      u32 sa = ((u32)(va - 1) & 3u) * 16u;                                     \
      u32 sb = ((u32)(vb - 1) & 3u) * 16u;                                     \
      u64 ha = va ? (0x3F80ull << sa) : 0ull;                                  \
      u64 hb = vb ? (0x3F80ull << sb) : 0ull;                                  \
      u32x4 e = {(u32)ha, (u32)(ha >> 32), (u32)hb, (u32)(hb >> 32)};          \
      *(u32x4*)(rowp + ((half * 64 + p * 16) ^ aswz)) = e;                     \
    }                                                                          \
  }
#define BARV6()                                                                \
  asm volatile("s_waitcnt vmcnt(6) lgkmcnt(0)" ::: "memory");                  \
  __builtin_amdgcn_s_barrier();                                                \
  __builtin_amdgcn_sched_barrier(0);
#define BARV0()                                                                \
  asm volatile("s_waitcnt vmcnt(0) lgkmcnt(0)" ::: "memory");                  \
  __builtin_amdgcn_s_barrier();                                                \
  __builtin_amdgcn_sched_barrier(0);
#define MFMA_STEP(AC, BC)                                                      \
  __builtin_amdgcn_s_setprio(1);                                               \
  _Pragma("unroll") for (int kk = 0; kk < 2; ++kk) {                           \
    bf16x8 af[4], bfv[4];                                                      \
    const int colb = (kk * 64 + fq * 16) ^ rswz;                               \
    _Pragma("unroll") for (int fm = 0; fm < 4; ++fm)                           \
      af[fm] = *(const bf16x8*)((AC) + (wr * 64 + fm * 16 + fr) * 128 + colb); \
    _Pragma("unroll") for (int fo = 0; fo < 4; ++fo)                           \
      bfv[fo] = *(const bf16x8*)((BC) + (wc * 64 + fo * 16 + fr) * 128 + colb);\
    _Pragma("unroll") for (int fm = 0; fm < 4; ++fm)                           \
      _Pragma("unroll") for (int fo = 0; fo < 4; ++fo)                         \
        acc[fm][fo] = __builtin_amdgcn_mfma_f32_16x16x32_bf16(                 \
            af[fm], bfv[fo], acc[fm][fo], 0, 0, 0);                            \
  }                                                                            \
  __builtin_amdgcn_s_setprio(0);
#define BODY(S, ACUR, BCUR, ANXT, RLA, RLB, RCA, RCB, BSTG)                    \
  {                                                                            \
    STAGE_B((S) + 2, BSTG);                                                    \
    RELLOAD((S) + 2, RLA, RLB);                                                \
    MFMA_STEP(ACUR, BCUR);                                                     \
    EXPAND_A(ANXT, RCA, RCB);                                                  \
    BARV6();                                                                   \
  }

  STAGE_B(0, Bb0);
  RELLOAD(0, rsA0, rsB0);
  STAGE_B(1, Bb1);
  RELLOAD(1, rsA1, rsB1);
  EXPAND_A(Ab0, rsA0, rsB0);
  BARV6();

  for (int s = 0; s < 60; s += 6) {
    BODY(s + 0, Ab0, Bb0, Ab1, rsA0, rsB0, rsA1, rsB1, Bb2);
    BODY(s + 1, Ab1, Bb1, Ab0, rsA1, rsB1, rsA0, rsB0, Bb0);
    BODY(s + 2, Ab0, Bb2, Ab1, rsA0, rsB0, rsA1, rsB1, Bb1);
    BODY(s + 3, Ab1, Bb0, Ab0, rsA1, rsB1, rsA0, rsB0, Bb2);
    BODY(s + 4, Ab0, Bb1, Ab1, rsA0, rsB0, rsA1, rsB1, Bb0);
    BODY(s + 5, Ab1, Bb2, Ab0, rsA1, rsB1, rsA0, rsB0, Bb1);
  }
  BODY(60, Ab0, Bb0, Ab1, rsA0, rsB0, rsA1, rsB1, Bb2);
  BODY(61, Ab1, Bb1, Ab0, rsA1, rsB1, rsA0, rsB0, Bb0);
  {
    MFMA_STEP(Ab0, Bb2);
    EXPAND_A(Ab1, rsA1, rsB1);
    BARV0();
  }
  {
    MFMA_STEP(Ab1, Bb0);
  }

  float* dst = ks ? part : out;
#pragma unroll
  for (int fm = 0; fm < 4; ++fm)
#pragma unroll
    for (int fo = 0; fo < 4; ++fo) {
      int n = nt * 128 + wr * 64 + fm * 16 + fq * 4;
      int o = ot * 128 + wc * 64 + fo * 16 + fr;
#pragma unroll
      for (int j = 0; j < 4; ++j)
        dst[(size_t)(b * NN + n + j) * DOUT + o] = acc[fm][fo][j];
    }
#undef BODY
#undef MFMA_STEP
#undef BARV6
#undef BARV0
#undef EXPAND_A
#undef RELLOAD
#undef STAGE_B
}

__global__ void k3_r4(float* __restrict__ out, const float* __restrict__ part,
                      const float* __restrict__ bias) {
  int i = blockIdx.x * 256 + threadIdx.x;
  float4 o = ((const float4*)out)[i];
  float4 p = ((const float4*)part)[i];
  float4 bv = ((const float4*)bias)[i & 63];
  float4 rr;
  rr.x = o.x + p.x + bv.x;
  rr.y = o.y + p.y + bv.y;
  rr.z = o.z + p.z + bv.z;
  rr.w = o.w + p.w + bv.w;
  ((float4*)out)[i] = rr;
}

extern "C" void kernel_launch(void* const* d_in, const int* in_sizes, int n_in,
                              void* d_out, int out_size, void* d_ws, size_t ws_size,
                              hipStream_t stream) {
  const float* x = (const float*)d_in[0];
  const int* rel = (const int*)d_in[2];
  const float* wgt = (const float*)d_in[3];
  const float* bias = (const float*)d_in[4];
  float* out = (float*)d_out;
  char* ws = (char*)d_ws;

  const size_t partb_bytes = (size_t)PART_ELEMS * 2 * 4;  // 4 bf16 partials
  const size_t need_big = (size_t)XW_BYTES + partb_bytes + WT_BYTES;
  if (ws_size >= need_big) {
    ushort* xwT = (ushort*)ws;
    ushort* partb = (ushort*)(ws + XW_BYTES);
    ushort* wT = (ushort*)(ws + XW_BYTES + partb_bytes);
    k0_wT<<<1024, 256, 0, stream>>>(wgt, wT);
    k1_xw<<<512, 512, 0, stream>>>(x, wT, xwT);
    k2_v2<<<256, 512, 0, stream>>>(rel, xwT, partb);
    k3_sum<<<4096, 256, 0, stream>>>(out, partb, bias);
  } else {
    ushort* xwT = (ushort*)ws;
    float* part = (float*)(ws + XW_BYTES);
    ushort* wT = (ushort*)(ws + XW_BYTES + PART_BYTES);
    k0_wT<<<1024, 256, 0, stream>>>(wgt, wT);
    k1_xw<<<512, 512, 0, stream>>>(x, wT, xwT);
    k2_r4<<<512, 256, 0, stream>>>(rel, xwT, out, part);
    k3_r4<<<4096, 256, 0, stream>>>(out, part, bias);
  }
}